// Round 4
// baseline (2650.744 us; speedup 1.0000x reference)
//
#include <hip/hip_runtime.h>
#include <cstdint>

// ---------------- fast device math (raw v_exp_f32 / v_rcp_f32) ----------------
__device__ __forceinline__ float fexp2(float x) { return __builtin_amdgcn_exp2f(x); }
__device__ __forceinline__ float frcp(float x)  { return __builtin_amdgcn_rcpf(x); }

__device__ __forceinline__ float fast_tanh(float x) {
    x = fminf(15.0f, fmaxf(-15.0f, x));
    float E = fexp2(x * 2.8853900817779268f);   // exp(2x) = 2^(2x*log2e)
    float d = E + 1.0f;
    float r = frcp(d);
    r = r * (2.0f - d * r);                      // Newton -> ~fp32 precise
    return (E - 1.0f) * r;
}

// ---------------- tiled fp32 GEMM: C[M][N] = act(A[M][K] @ W[K][N] + bias) ----
#define BM 64
#define BN 64
#define BK 16

template<bool TANH>
__global__ __launch_bounds__(256) void gemm_bias(
    const float* __restrict__ A, const float* __restrict__ W,
    const float* __restrict__ bias, float* __restrict__ C,
    int M, int N, int K)
{
    __shared__ float As[BK][BM + 4];
    __shared__ float Bs[BK][BN + 4];

    const int tid = threadIdx.x;
    const int tx = tid & 15;
    const int ty = tid >> 4;
    const int m0 = blockIdx.y * BM;
    const int n0 = blockIdx.x * BN;

    float acc[4][4] = {};

    for (int k0 = 0; k0 < K; k0 += BK) {
        #pragma unroll
        for (int ld = 0; ld < 4; ++ld) {
            int e  = tid + ld * 256;
            int kk = e & 15, mm = e >> 4;
            int kg = k0 + kk;
            As[kk][mm] = (kg < K) ? A[(size_t)(m0 + mm) * K + kg] : 0.0f;
        }
        #pragma unroll
        for (int ld = 0; ld < 4; ++ld) {
            int e  = tid + ld * 256;
            int nn = e & 63, kk = e >> 6;
            int kg = k0 + kk, ng = n0 + nn;
            Bs[kk][nn] = (kg < K && ng < N) ? W[(size_t)kg * N + ng] : 0.0f;
        }
        __syncthreads();

        #pragma unroll
        for (int kk = 0; kk < BK; ++kk) {
            float4 a  = *(const float4*)&As[kk][ty * 4];
            float4 bq = *(const float4*)&Bs[kk][tx * 4];
            float av[4] = {a.x, a.y, a.z, a.w};
            float bv[4] = {bq.x, bq.y, bq.z, bq.w};
            #pragma unroll
            for (int i2 = 0; i2 < 4; ++i2)
                #pragma unroll
                for (int j2 = 0; j2 < 4; ++j2)
                    acc[i2][j2] += av[i2] * bv[j2];
        }
        __syncthreads();
    }

    const int cbase = n0 + tx * 4;
    if (cbase >= N) return;

    float bb[4];
    if (cbase + 3 < N) {
        float4 b4 = *(const float4*)&bias[cbase];
        bb[0] = b4.x; bb[1] = b4.y; bb[2] = b4.z; bb[3] = b4.w;
    } else {
        #pragma unroll
        for (int e = 0; e < 4; ++e) bb[e] = (cbase + e < N) ? bias[cbase + e] : 0.0f;
    }

    #pragma unroll
    for (int i2 = 0; i2 < 4; ++i2) {
        int row = m0 + ty * 4 + i2;
        float o[4];
        #pragma unroll
        for (int j2 = 0; j2 < 4; ++j2) {
            float v = acc[i2][j2] + bb[j2];
            o[j2] = TANH ? fast_tanh(v) : v;
        }
        if (cbase + 3 < N) {
            float4 o4 = {o[0], o[1], o[2], o[3]};
            *(float4*)&C[(size_t)row * N + cbase] = o4;
        } else {
            #pragma unroll
            for (int j2 = 0; j2 < 4; ++j2)
                if (cbase + j2 < N) C[(size_t)row * N + cbase + j2] = o[j2];
        }
    }
}

// ---------------- decoder layer 1 (K=4) --------------------------------------
__global__ __launch_bounds__(256) void dec_l1(
    const float* __restrict__ Mo, const float* __restrict__ Wd,
    const float* __restrict__ bd, float* __restrict__ O)
{
    int idx = blockIdx.x * 256 + threadIdx.x;
    int r  = idx / 125;
    int c4 = (idx % 125) * 4;
    float4 m = *(const float4*)&Mo[(size_t)r * 4];
    float4 w0 = *(const float4*)&Wd[0 * 500 + c4];
    float4 w1 = *(const float4*)&Wd[1 * 500 + c4];
    float4 w2 = *(const float4*)&Wd[2 * 500 + c4];
    float4 w3 = *(const float4*)&Wd[3 * 500 + c4];
    float4 b  = *(const float4*)&bd[c4];
    float o0 = b.x + m.x * w0.x + m.y * w1.x + m.z * w2.x + m.w * w3.x;
    float o1 = b.y + m.x * w0.y + m.y * w1.y + m.z * w2.y + m.w * w3.y;
    float o2 = b.z + m.x * w0.z + m.y * w1.z + m.z * w2.z + m.w * w3.z;
    float o3 = b.w + m.x * w0.w + m.y * w1.w + m.z * w2.w + m.w * w3.w;
    float4 o = {fast_tanh(o0), fast_tanh(o1), fast_tanh(o2), fast_tanh(o3)};
    *(float4*)&O[(size_t)r * 500 + c4] = o;
}

// ---------------- LTC scan with LDS sigmoid LUT ------------------------------
// 1 block/batch, 4 waves (256 thr), lane = unit j (redundant across waves).
// Wave w owns presynaptic i in [16w,16w+16). sigmoid via 2048-entry f32 LUT
// over y in [-20,20] + analytic-slope correction  sig = c0 + fr*D*c0*(1-c0)
// (interp err ~2e-5). No transcendentals in the hot loop. Cross-wave reduce:
// conflict-free f32 partial arrays, 1 barrier per unfold, double-buffered.
#define SEQ_T 512
#define LUT_N 2048
#define LUT_YMIN -20.0f
#define LUT_INVD 51.2f            // LUT_N / 40
#define LUT_D    0.01953125f      // 40 / LUT_N
#define LUT_BIAS 1024.0f          // -YMIN * INVD
#define LUT_TMAX 2047.4f

__global__ __launch_bounds__(256, 1) void ltc_scan(
    const float* __restrict__ h,       // [32][512][20]
    const float* __restrict__ gleak, const float* __restrict__ vleak,
    const float* __restrict__ cm,
    const float* __restrict__ w,  const float* __restrict__ mu,
    const float* __restrict__ sg, const float* __restrict__ erev,
    const float* __restrict__ sw,  const float* __restrict__ smu,
    const float* __restrict__ ssg, const float* __restrict__ serev,
    const float* __restrict__ in_w, const float* __restrict__ in_b,
    const float* __restrict__ out_w, const float* __restrict__ out_b,
    float* __restrict__ motor)         // [32][512][4]
{
    const int b   = blockIdx.x;
    const int tid = threadIdx.x;
    const int w4  = tid >> 6;          // wave 0..3
    const int j   = tid & 63;          // postsynaptic unit

    __shared__ float lut[LUT_N];       // 8 KB
    __shared__ float AN[2][4][64];     // 2 KB  conflict-free partials
    __shared__ float AD[2][4][64];     // 2 KB

    // build sigmoid table (one-time, high precision)
    const float LOG2E = 1.4426950408889634f;
    for (int k = tid; k < LUT_N; k += 256) {
        float y = LUT_YMIN + (float)k * LUT_D;
        float E = fexp2(-y * LOG2E);
        float d = 1.0f + E;
        float r = frcp(d);
        r = r * (2.0f - d * r);
        lut[k] = r;
    }

    // unfold params for (i = 16*w4 + r, j), index-space folded:
    // t = v * (sigma*INVD) + (BIAS - mu*sigma*INVD)
    float A2[16], B2[16], Wp[16], WE[16];
    #pragma unroll
    for (int r = 0; r < 16; ++r) {
        int i = 16 * w4 + r;
        float s = sg[i * 64 + j];
        A2[r] = s * LUT_INVD;
        B2[r] = LUT_BIAS - mu[i * 64 + j] * s * LUT_INVD;
        Wp[r] = w[i * 64 + j];
        WE[r] = Wp[r] * erev[i * 64 + j];
    }
    // sensory params: i = 5*w4 + r
    float sA2[5], sB2[5], sWp[5], sWE[5], uw[5], ub[5];
    #pragma unroll
    for (int r = 0; r < 5; ++r) {
        int i = 5 * w4 + r;
        float s = ssg[i * 64 + j];
        sA2[r] = s * LUT_INVD;
        sB2[r] = LUT_BIAS - smu[i * 64 + j] * s * LUT_INVD;
        sWp[r] = sw[i * 64 + j];
        sWE[r] = sWp[r] * serev[i * 64 + j];
        uw[r]  = in_w[i];
        ub[r]  = in_b[i];
    }

    const float cmt  = cm[j] * 6.0f;
    const float gl   = gleak[j];
    const float glvl = gl * vleak[j];
    const float ow   = out_w[j & 3], ob = out_b[j & 3];

    float vj = 0.0f;
    const float* hb = h + (size_t)b * SEQ_T * 20;
    float* mb = motor + (size_t)b * SEQ_T * 4;

    float u_cur[5], u_nxt[5];
    #pragma unroll
    for (int r = 0; r < 5; ++r) u_cur[r] = hb[5 * w4 + r];

    __syncthreads();   // table ready

    int buf = 0;
    for (int t = 0; t < SEQ_T; ++t) {
        int tn = (t + 1 < SEQ_T) ? (t + 1) : t;
        #pragma unroll
        for (int r = 0; r < 5; ++r) u_nxt[r] = hb[tn * 20 + 5 * w4 + r];

        // sensory partial for this wave (LUT sigmoid)
        float ns = 0.0f, dss = 0.0f;
        #pragma unroll
        for (int r = 0; r < 5; ++r) {
            float ui = fmaf(u_cur[r], uw[r], ub[r]);
            float tt = fmaf(ui, sA2[r], sB2[r]);
            tt = fminf(fmaxf(tt, 0.0f), LUT_TMAX);
            float fl = floorf(tt);
            float fr = tt - fl;
            float c0 = lut[(uint)fl];
            float q  = fr * LUT_D;
            float u1 = fmaf(-c0, q, q);          // q*(1-c0)
            float s  = fmaf(c0, u1, c0);         // c0 + c0*q*(1-c0)
            ns  = fmaf(sWE[r], s, ns);
            dss = fmaf(sWp[r], s, dss);
        }

        #pragma unroll 1
        for (int uf = 0; uf < 6; ++uf) {
            float an0 = ns, an1 = 0.0f, ad0 = dss, ad1 = 0.0f;
            #pragma unroll
            for (int r = 0; r < 16; ++r) {
                float vi = __uint_as_float(
                    __builtin_amdgcn_readlane(__float_as_uint(vj), 16 * w4 + r));
                float tt = fmaf(vi, A2[r], B2[r]);
                tt = fminf(fmaxf(tt, 0.0f), LUT_TMAX);
                float fl = floorf(tt);
                float fr = tt - fl;
                float c0 = lut[(uint)fl];
                float q  = fr * LUT_D;
                float u1 = fmaf(-c0, q, q);
                float s  = fmaf(c0, u1, c0);
                if (r & 1) { an1 = fmaf(WE[r], s, an1); ad1 = fmaf(Wp[r], s, ad1); }
                else       { an0 = fmaf(WE[r], s, an0); ad0 = fmaf(Wp[r], s, ad0); }
            }
            AN[buf][w4][j] = an0 + an1;
            AD[buf][w4][j] = ad0 + ad1;
            __syncthreads();
            float a0 = AN[buf][0][j], a1 = AN[buf][1][j];
            float a2 = AN[buf][2][j], a3 = AN[buf][3][j];
            float d0 = AD[buf][0][j], d1 = AD[buf][1][j];
            float d2 = AD[buf][2][j], d3 = AD[buf][3][j];
            float num = fmaf(cmt, vj, glvl) + ((a0 + a1) + (a2 + a3));
            float den = cmt + gl + ((d0 + d1) + (d2 + d3)) + 1e-8f;
            vj = num * frcp(den);
            buf ^= 1;
        }

        if (w4 == 0 && j < 4) mb[t * 4 + j] = fmaf(vj, ow, ob);

        #pragma unroll
        for (int r = 0; r < 5; ++r) u_cur[r] = u_nxt[r];
    }
}

// ---------------- launch --------------------------------------------------
extern "C" void kernel_launch(void* const* d_in, const int* in_sizes, int n_in,
                              void* d_out, int out_size, void* d_ws, size_t ws_size,
                              hipStream_t stream) {
    const float* x      = (const float*)d_in[0];
    const float* enc_w0 = (const float*)d_in[1];
    const float* enc_b0 = (const float*)d_in[2];
    const float* enc_w1 = (const float*)d_in[3];
    const float* enc_b1 = (const float*)d_in[4];
    const float* enc_w2 = (const float*)d_in[5];
    const float* enc_b2 = (const float*)d_in[6];
    const float* dec_w0 = (const float*)d_in[7];
    const float* dec_b0 = (const float*)d_in[8];
    const float* dec_w1 = (const float*)d_in[9];
    const float* dec_b1 = (const float*)d_in[10];
    const float* dec_w2 = (const float*)d_in[11];
    const float* dec_b2 = (const float*)d_in[12];
    const float* gleak  = (const float*)d_in[13];
    const float* vleak  = (const float*)d_in[14];
    const float* cm     = (const float*)d_in[15];
    const float* w      = (const float*)d_in[16];
    const float* mu     = (const float*)d_in[17];
    const float* sigma  = (const float*)d_in[18];
    const float* erev   = (const float*)d_in[19];
    const float* sw     = (const float*)d_in[20];
    const float* smu    = (const float*)d_in[21];
    const float* ssigma = (const float*)d_in[22];
    const float* serev  = (const float*)d_in[23];
    const float* in_w   = (const float*)d_in[24];
    const float* in_b   = (const float*)d_in[25];
    const float* out_w  = (const float*)d_in[26];
    const float* out_b  = (const float*)d_in[27];

    float* ws   = (float*)d_ws;
    float* buf1 = ws;                       // 16384*500
    float* buf2 = ws + 8192000;             // 16384*500
    float* hbuf = ws + 16384000;            // 16384*20
    float* mbuf = ws + 16384000 + 327680;   // 16384*4

    dim3 blk(256);
    // encoder
    gemm_bias<true ><<<dim3(8, 256), blk, 0, stream>>>(x,    enc_w0, enc_b0, buf1, 16384, 500, 39);
    gemm_bias<true ><<<dim3(8, 256), blk, 0, stream>>>(buf1, enc_w1, enc_b1, buf2, 16384, 500, 500);
    gemm_bias<false><<<dim3(1, 256), blk, 0, stream>>>(buf2, enc_w2, enc_b2, hbuf, 16384, 20, 500);
    // LTC scan
    ltc_scan<<<dim3(32), dim3(256), 0, stream>>>(hbuf, gleak, vleak, cm, w, mu, sigma, erev,
                                                 sw, smu, ssigma, serev, in_w, in_b, out_w, out_b, mbuf);
    // decoder
    dec_l1<<<dim3(8000), blk, 0, stream>>>(mbuf, dec_w0, dec_b0, buf1);
    gemm_bias<true ><<<dim3(8, 256), blk, 0, stream>>>(buf1, dec_w1, dec_b1, buf2, 16384, 500, 500);
    gemm_bias<false><<<dim3(1, 256), blk, 0, stream>>>(buf2, dec_w2, dec_b2, (float*)d_out, 16384, 30, 500);
}

// Round 5
// 2239.427 us; speedup vs baseline: 1.1837x; 1.1837x over previous
//
#include <hip/hip_runtime.h>
#include <cstdint>

// ---------------- fast device math (raw v_exp_f32 / v_rcp_f32) ----------------
__device__ __forceinline__ float fexp2(float x) { return __builtin_amdgcn_exp2f(x); }
__device__ __forceinline__ float frcp(float x)  { return __builtin_amdgcn_rcpf(x); }

__device__ __forceinline__ float fast_tanh(float x) {
    x = fminf(15.0f, fmaxf(-15.0f, x));
    float E = fexp2(x * 2.8853900817779268f);   // exp(2x) = 2^(2x*log2e)
    float d = E + 1.0f;
    float r = frcp(d);
    r = r * (2.0f - d * r);                      // Newton -> ~fp32 precise
    return (E - 1.0f) * r;
}

// ---------------- tiled fp32 GEMM: C[M][N] = act(A[M][K] @ W[K][N] + bias) ----
#define BM 64
#define BN 64
#define BK 16

template<bool TANH>
__global__ __launch_bounds__(256) void gemm_bias(
    const float* __restrict__ A, const float* __restrict__ W,
    const float* __restrict__ bias, float* __restrict__ C,
    int M, int N, int K)
{
    __shared__ float As[BK][BM + 4];
    __shared__ float Bs[BK][BN + 4];

    const int tid = threadIdx.x;
    const int tx = tid & 15;
    const int ty = tid >> 4;
    const int m0 = blockIdx.y * BM;
    const int n0 = blockIdx.x * BN;

    float acc[4][4] = {};

    for (int k0 = 0; k0 < K; k0 += BK) {
        #pragma unroll
        for (int ld = 0; ld < 4; ++ld) {
            int e  = tid + ld * 256;
            int kk = e & 15, mm = e >> 4;
            int kg = k0 + kk;
            As[kk][mm] = (kg < K) ? A[(size_t)(m0 + mm) * K + kg] : 0.0f;
        }
        #pragma unroll
        for (int ld = 0; ld < 4; ++ld) {
            int e  = tid + ld * 256;
            int nn = e & 63, kk = e >> 6;
            int kg = k0 + kk, ng = n0 + nn;
            Bs[kk][nn] = (kg < K && ng < N) ? W[(size_t)kg * N + ng] : 0.0f;
        }
        __syncthreads();

        #pragma unroll
        for (int kk = 0; kk < BK; ++kk) {
            float4 a  = *(const float4*)&As[kk][ty * 4];
            float4 bq = *(const float4*)&Bs[kk][tx * 4];
            float av[4] = {a.x, a.y, a.z, a.w};
            float bv[4] = {bq.x, bq.y, bq.z, bq.w};
            #pragma unroll
            for (int i2 = 0; i2 < 4; ++i2)
                #pragma unroll
                for (int j2 = 0; j2 < 4; ++j2)
                    acc[i2][j2] += av[i2] * bv[j2];
        }
        __syncthreads();
    }

    const int cbase = n0 + tx * 4;
    if (cbase >= N) return;

    float bb[4];
    if (cbase + 3 < N) {
        float4 b4 = *(const float4*)&bias[cbase];
        bb[0] = b4.x; bb[1] = b4.y; bb[2] = b4.z; bb[3] = b4.w;
    } else {
        #pragma unroll
        for (int e = 0; e < 4; ++e) bb[e] = (cbase + e < N) ? bias[cbase + e] : 0.0f;
    }

    #pragma unroll
    for (int i2 = 0; i2 < 4; ++i2) {
        int row = m0 + ty * 4 + i2;
        float o[4];
        #pragma unroll
        for (int j2 = 0; j2 < 4; ++j2) {
            float v = acc[i2][j2] + bb[j2];
            o[j2] = TANH ? fast_tanh(v) : v;
        }
        if (cbase + 3 < N) {
            float4 o4 = {o[0], o[1], o[2], o[3]};
            *(float4*)&C[(size_t)row * N + cbase] = o4;
        } else {
            #pragma unroll
            for (int j2 = 0; j2 < 4; ++j2)
                if (cbase + j2 < N) C[(size_t)row * N + cbase + j2] = o[j2];
        }
    }
}

// ---------------- decoder layer 1 (K=4) --------------------------------------
__global__ __launch_bounds__(256) void dec_l1(
    const float* __restrict__ Mo, const float* __restrict__ Wd,
    const float* __restrict__ bd, float* __restrict__ O)
{
    int idx = blockIdx.x * 256 + threadIdx.x;
    int r  = idx / 125;
    int c4 = (idx % 125) * 4;
    float4 m = *(const float4*)&Mo[(size_t)r * 4];
    float4 w0 = *(const float4*)&Wd[0 * 500 + c4];
    float4 w1 = *(const float4*)&Wd[1 * 500 + c4];
    float4 w2 = *(const float4*)&Wd[2 * 500 + c4];
    float4 w3 = *(const float4*)&Wd[3 * 500 + c4];
    float4 b  = *(const float4*)&bd[c4];
    float o0 = b.x + m.x * w0.x + m.y * w1.x + m.z * w2.x + m.w * w3.x;
    float o1 = b.y + m.x * w0.y + m.y * w1.y + m.z * w2.y + m.w * w3.y;
    float o2 = b.z + m.x * w0.z + m.y * w1.z + m.z * w2.z + m.w * w3.z;
    float o3 = b.w + m.x * w0.w + m.y * w1.w + m.z * w2.w + m.w * w3.w;
    float4 o = {fast_tanh(o0), fast_tanh(o1), fast_tanh(o2), fast_tanh(o3)};
    *(float4*)&O[(size_t)r * 500 + c4] = o;
}

// ---------------- LTC scan: 1 block/batch, 8 waves (512 thr), lane = unit j --
// Wave w owns presynaptic i in [8w, 8w+8). Every wave keeps the full v vector
// (lane j holds v_j, identical across waves); v_i comes from v_readlane.
// exp-based sigmoid (trans units are per-SIMD: 4x parallel; LDS LUT was the
// R3 mistake - it serialized on the per-CU LDS pipe, 2.7e7 conflict cycles).
// Reduce: conflict-free f32 partials AN/AD[2][8][64], ONE barrier per unfold,
// double-buffered. 2 waves/SIMD so waves hide each other's barrier/LDS/trans
// latency. Sensory synapses: waves 0-3 take 3, waves 4-7 take 2 (=20), folded
// into every unfold's reduce as the partial-accumulator init.
#define SEQ_T 512

__global__ __launch_bounds__(512, 2) void ltc_scan(
    const float* __restrict__ h,       // [32][512][20]
    const float* __restrict__ gleak, const float* __restrict__ vleak,
    const float* __restrict__ cm,
    const float* __restrict__ w,  const float* __restrict__ mu,
    const float* __restrict__ sg, const float* __restrict__ erev,
    const float* __restrict__ sw,  const float* __restrict__ smu,
    const float* __restrict__ ssg, const float* __restrict__ serev,
    const float* __restrict__ in_w, const float* __restrict__ in_b,
    const float* __restrict__ out_w, const float* __restrict__ out_b,
    float* __restrict__ motor)         // [32][512][4]
{
    const int b   = blockIdx.x;
    const int tid = threadIdx.x;
    const int w8  = tid >> 6;          // wave 0..7
    const int j   = tid & 63;          // postsynaptic unit

    const float LOG2E = 1.4426950408889634f;

    __shared__ float AN[2][8][64];     // 2 KB  conflict-free partials
    __shared__ float AD[2][8][64];     // 2 KB

    // unfold params for (i = 8*w8 + r, j):  x = B1 - vi*A1, E=2^x, s=1/(1+E)
    float A1[8], B1[8], Wp[8], WE[8];
    #pragma unroll
    for (int r = 0; r < 8; ++r) {
        int i = 8 * w8 + r;
        float s = sg[i * 64 + j];
        A1[r] = s * LOG2E;
        B1[r] = mu[i * 64 + j] * s * LOG2E;
        Wp[r] = w[i * 64 + j];
        WE[r] = Wp[r] * erev[i * 64 + j];
    }
    // sensory params: i = w8, w8+8, and (w8<4 ? w8+16 : masked)
    float sA[3], sB[3], sWp[3], sWE[3], uw[3], ub[3];
    int   sI[3];
    #pragma unroll
    for (int r = 0; r < 3; ++r) {
        int i = w8 + 8 * r;
        bool live = (i < 20);
        sI[r] = live ? i : 0;
        float s = ssg[sI[r] * 64 + j];
        sA[r]  = s * LOG2E;
        sB[r]  = smu[sI[r] * 64 + j] * s * LOG2E;
        sWp[r] = live ? sw[sI[r] * 64 + j] : 0.0f;
        sWE[r] = live ? sWp[r] * serev[sI[r] * 64 + j] : 0.0f;
        uw[r]  = in_w[sI[r]];
        ub[r]  = in_b[sI[r]];
    }

    const float cmt  = cm[j] * 6.0f;
    const float gl   = gleak[j];
    const float glvl = gl * vleak[j];
    const float ow   = out_w[j & 3], ob = out_b[j & 3];

    float vj = 0.0f;
    const float* hb = h + (size_t)b * SEQ_T * 20;
    float* mb = motor + (size_t)b * SEQ_T * 4;

    float u_cur[3], u_nxt[3];
    #pragma unroll
    for (int r = 0; r < 3; ++r) u_cur[r] = hb[sI[r]];

    int buf = 0;
    for (int t = 0; t < SEQ_T; ++t) {
        int tn = (t + 1 < SEQ_T) ? (t + 1) : t;
        #pragma unroll
        for (int r = 0; r < 3; ++r) u_nxt[r] = hb[tn * 20 + sI[r]];

        // sensory partial for this wave (init for every unfold's accumulator)
        float ns = 0.0f, ds = 0.0f;
        #pragma unroll
        for (int r = 0; r < 3; ++r) {
            float ui = fmaf(u_cur[r], uw[r], ub[r]);
            float x  = sB[r] - ui * sA[r];
            float E  = fexp2(x);
            float s  = frcp(1.0f + E);
            ns = fmaf(sWE[r], s, ns);
            ds = fmaf(sWp[r], s, ds);
        }

        #pragma unroll 1
        for (int uf = 0; uf < 6; ++uf) {
            float an = ns, ad = ds;
            #pragma unroll
            for (int r = 0; r < 8; ++r) {
                float vi = __uint_as_float(
                    __builtin_amdgcn_readlane(__float_as_uint(vj), 8 * w8 + r));
                float x = B1[r] - vi * A1[r];
                float E = fexp2(x);
                float s = frcp(1.0f + E);
                an = fmaf(WE[r], s, an);
                ad = fmaf(Wp[r], s, ad);
            }
            AN[buf][w8][j] = an;
            AD[buf][w8][j] = ad;
            __syncthreads();
            float num = fmaf(cmt, vj, glvl);
            float den = cmt + gl + 1e-8f;
            #pragma unroll
            for (int q = 0; q < 8; ++q) { num += AN[buf][q][j]; den += AD[buf][q][j]; }
            vj = num * frcp(den);
            buf ^= 1;
        }

        if (w8 == 0 && j < 4) mb[t * 4 + j] = fmaf(vj, ow, ob);

        #pragma unroll
        for (int r = 0; r < 3; ++r) u_cur[r] = u_nxt[r];
    }
}

// ---------------- launch --------------------------------------------------
extern "C" void kernel_launch(void* const* d_in, const int* in_sizes, int n_in,
                              void* d_out, int out_size, void* d_ws, size_t ws_size,
                              hipStream_t stream) {
    const float* x      = (const float*)d_in[0];
    const float* enc_w0 = (const float*)d_in[1];
    const float* enc_b0 = (const float*)d_in[2];
    const float* enc_w1 = (const float*)d_in[3];
    const float* enc_b1 = (const float*)d_in[4];
    const float* enc_w2 = (const float*)d_in[5];
    const float* enc_b2 = (const float*)d_in[6];
    const float* dec_w0 = (const float*)d_in[7];
    const float* dec_b0 = (const float*)d_in[8];
    const float* dec_w1 = (const float*)d_in[9];
    const float* dec_b1 = (const float*)d_in[10];
    const float* dec_w2 = (const float*)d_in[11];
    const float* dec_b2 = (const float*)d_in[12];
    const float* gleak  = (const float*)d_in[13];
    const float* vleak  = (const float*)d_in[14];
    const float* cm     = (const float*)d_in[15];
    const float* w      = (const float*)d_in[16];
    const float* mu     = (const float*)d_in[17];
    const float* sigma  = (const float*)d_in[18];
    const float* erev   = (const float*)d_in[19];
    const float* sw     = (const float*)d_in[20];
    const float* smu    = (const float*)d_in[21];
    const float* ssigma = (const float*)d_in[22];
    const float* serev  = (const float*)d_in[23];
    const float* in_w   = (const float*)d_in[24];
    const float* in_b   = (const float*)d_in[25];
    const float* out_w  = (const float*)d_in[26];
    const float* out_b  = (const float*)d_in[27];

    float* ws   = (float*)d_ws;
    float* buf1 = ws;                       // 16384*500
    float* buf2 = ws + 8192000;             // 16384*500
    float* hbuf = ws + 16384000;            // 16384*20
    float* mbuf = ws + 16384000 + 327680;   // 16384*4

    dim3 blk(256);
    // encoder
    gemm_bias<true ><<<dim3(8, 256), blk, 0, stream>>>(x,    enc_w0, enc_b0, buf1, 16384, 500, 39);
    gemm_bias<true ><<<dim3(8, 256), blk, 0, stream>>>(buf1, enc_w1, enc_b1, buf2, 16384, 500, 500);
    gemm_bias<false><<<dim3(1, 256), blk, 0, stream>>>(buf2, enc_w2, enc_b2, hbuf, 16384, 20, 500);
    // LTC scan
    ltc_scan<<<dim3(32), dim3(512), 0, stream>>>(hbuf, gleak, vleak, cm, w, mu, sigma, erev,
                                                 sw, smu, ssigma, serev, in_w, in_b, out_w, out_b, mbuf);
    // decoder
    dec_l1<<<dim3(8000), blk, 0, stream>>>(mbuf, dec_w0, dec_b0, buf1);
    gemm_bias<true ><<<dim3(8, 256), blk, 0, stream>>>(buf1, dec_w1, dec_b1, buf2, 16384, 500, 500);
    gemm_bias<false><<<dim3(1, 256), blk, 0, stream>>>(buf2, dec_w2, dec_b2, (float*)d_out, 16384, 30, 500);
}